// Round 1
// baseline (2344.127 us; speedup 1.0000x reference)
//
#include <hip/hip_runtime.h>
#include <math.h>

#define NTOT 32000000   // 4*128*250*250

__device__ __forceinline__ float gelu_f(float v) {
    return 0.5f * v * (1.0f + tanhf(0.7978845608028654f * (v + 0.044715f * v * v * v)));
}
__device__ __forceinline__ float sigmoid_f(float v) {
    return 1.0f / (1.0f + expf(-v));
}

// ---------- S4D discretization: per (h,m): w = exp(dt*A), C2 = 2*C*(exp(dtA)-1)/A ----------
__global__ void wc_kernel(const float* __restrict__ log_dt, const float* __restrict__ logA_re,
                          const float* __restrict__ A_im, const float* __restrict__ C_re,
                          const float* __restrict__ C_im, float* __restrict__ wC) {
    int t = blockIdx.x * 256 + threadIdx.x;
    if (t >= 128 * 32) return;
    int h = t >> 5, m = t & 31;
    float dt  = expf(log_dt[h]);
    float are = -expf(logA_re[t]);
    float aim = A_im[t];
    float er  = expf(dt * are);
    float wr  = er * cosf(dt * aim);
    float wi  = er * sinf(dt * aim);
    float e1r = wr - 1.0f, e1i = wi;              // exp(dtA) - 1
    float inv = 1.0f / (are * are + aim * aim);
    float qr  = (e1r * are + e1i * aim) * inv;    // (exp(dtA)-1)/A
    float qi  = (e1i * are - e1r * aim) * inv;
    float cre = C_re[t], cim = C_im[t];
    wC[h * 128 + m]      = wr;
    wC[h * 128 + 32 + m] = wi;
    wC[h * 128 + 64 + m] = 2.0f * (cre * qr - cim * qi);
    wC[h * 128 + 96 + m] = 2.0f * (cre * qi + cim * qr);
}

// ---------- u[(b*250+s)*32000 + n*250 + k] = x[((b*128+n)*250+k)*250 + s] ----------
__global__ void transpose_in_kernel(const float* __restrict__ x, float* __restrict__ u) {
    __shared__ float tile[32][33];
    int kt = blockIdx.x, st = blockIdx.y;
    int bn = blockIdx.z; int b = bn >> 7, n = bn & 127;
    int tx = threadIdx.x & 31, ty = threadIdx.x >> 5;
    const float* xb = x + (long)((b * 128 + n) * 250) * 250;
    float* ub = u + (long)(b * 250) * 32000 + n * 250;
#pragma unroll
    for (int j = 0; j < 4; ++j) {
        int k = kt * 32 + ty + j * 8;
        int s = st * 32 + tx;
        if (k < 250 && s < 250) tile[ty + j * 8][tx] = xb[k * 250 + s];
    }
    __syncthreads();
#pragma unroll
    for (int j = 0; j < 4; ++j) {
        int k = kt * 32 + tx;
        int s = st * 32 + ty + j * 8;
        if (k < 250 && s < 250) ub[(long)s * 32000 + k] = tile[tx][ty + j * 8];
    }
}

// ---------- causal S4D conv via recurrence, + D*u, GELU; IN-PLACE on A [seq][h][l] ----------
__global__ __launch_bounds__(256, 2)
void conv_kernel(float* __restrict__ A, const float* __restrict__ wC,
                 const float* __restrict__ Dv) {
    __shared__ float su[256][17];
    const int tid = threadIdx.x;
    const int seq0 = blockIdx.x << 8;
    const int h = blockIdx.y;
    const float* wc = wC + (h << 7);
    float wr[32], wi[32], cr[32], ci[32], sr[32], si[32];
#pragma unroll
    for (int m = 0; m < 32; ++m) {
        wr[m] = wc[m]; wi[m] = wc[32 + m]; cr[m] = wc[64 + m]; ci[m] = wc[96 + m];
        sr[m] = 0.0f; si[m] = 0.0f;
    }
    const float Dh = Dv[h];
#pragma unroll 1
    for (int lt = 0; lt < 16; ++lt) {
        const int l0 = lt << 4;
        const int len = (l0 + 16 <= 250) ? 16 : (250 - l0);
#pragma unroll 1
        for (int i = tid; i < 4096; i += 256) {
            int rr = i >> 4, ll = i & 15;
            if (ll < len) {
                int seq = seq0 + rr; if (seq > 999) seq = 999;
                su[rr][ll] = A[(seq * 128 + h) * 250 + l0 + ll];
            }
        }
        __syncthreads();
#pragma unroll 1
        for (int jj = 0; jj < len; ++jj) {
            const float u = su[tid][jj];
            float a[4] = {0.f, 0.f, 0.f, 0.f};
#pragma unroll
            for (int m = 0; m < 32; ++m) {
                float nr = fmaf(wr[m], sr[m], fmaf(-wi[m], si[m], u));
                float ni = fmaf(wr[m], si[m], wi[m] * sr[m]);
                sr[m] = nr; si[m] = ni;
                a[m & 3] = fmaf(cr[m], nr, fmaf(-ci[m], ni, a[m & 3]));
            }
            float y = (a[0] + a[1]) + (a[2] + a[3]) + Dh * u;
            su[tid][jj] = gelu_f(y);
        }
        __syncthreads();
#pragma unroll 1
        for (int i = tid; i < 4096; i += 256) {
            int rr = i >> 4, ll = i & 15;
            int seq = seq0 + rr;
            if (ll < len && seq < 1000)
                A[(seq * 128 + h) * 250 + l0 + ll] = su[rr][ll];
        }
        __syncthreads();
    }
}

// ---------- z = ow @ y + ob (256 out ch), GLU -> 128 ch; IN-PLACE on A [seq][h][l] ----------
__global__ __launch_bounds__(256)
void outlin_kernel(float* __restrict__ A, const float* __restrict__ ow,
                   const float* __restrict__ ob) {
    __shared__ __align__(16) float ows[32 * 260];  // [hh][o], stride 260
    __shared__ __align__(16) float ys[32 * 36];    // [hh][l], stride 36
    const int tid = threadIdx.x;
    const int lt = blockIdx.x;     // 0..7
    const int seq = blockIdx.y;    // 0..999
    const int l0g = lt * 32;
    const int oq = tid & 31, lg = tid >> 5;
    const int o0 = oq * 4, ll0 = lg * 4;
    float acc1[4][4] = {{0}}, acc2[4][4] = {{0}};
#pragma unroll 1
    for (int hc = 0; hc < 4; ++hc) {
        const int h0 = hc * 32;
        __syncthreads();
        for (int i = tid; i < 8192; i += 256) {
            int o = i >> 5, hh = i & 31;
            ows[hh * 260 + o] = ow[o * 128 + h0 + hh];
        }
        for (int i = tid; i < 1024; i += 256) {
            int hh = i >> 5, ll = i & 31;
            int l = l0g + ll;
            ys[hh * 36 + ll] = (l < 250) ? A[(seq * 128 + h0 + hh) * 250 + l] : 0.f;
        }
        __syncthreads();
#pragma unroll 1
        for (int hh = 0; hh < 32; ++hh) {
            const float4 w1 = *(const float4*)&ows[hh * 260 + o0];
            const float4 w2 = *(const float4*)&ows[hh * 260 + 128 + o0];
            const float4 yv = *(const float4*)&ys[hh * 36 + ll0];
            const float wA[8] = {w1.x, w1.y, w1.z, w1.w, w2.x, w2.y, w2.z, w2.w};
            const float yA[4] = {yv.x, yv.y, yv.z, yv.w};
#pragma unroll
            for (int j = 0; j < 4; ++j)
#pragma unroll
                for (int i = 0; i < 4; ++i) {
                    acc1[j][i] = fmaf(wA[j], yA[i], acc1[j][i]);
                    acc2[j][i] = fmaf(wA[4 + j], yA[i], acc2[j][i]);
                }
        }
    }
    float ob1[4], ob2[4];
#pragma unroll
    for (int j = 0; j < 4; ++j) { ob1[j] = ob[o0 + j]; ob2[j] = ob[128 + o0 + j]; }
#pragma unroll
    for (int j = 0; j < 4; ++j)
#pragma unroll
        for (int i = 0; i < 4; ++i) {
            int l = l0g + ll0 + i;
            if (l < 250) {
                float z1 = acc1[j][i] + ob1[j];
                float z2 = acc2[j][i] + ob2[j];
                A[(seq * 128 + o0 + j) * 250 + l] = z1 * sigmoid_f(z2);
            }
        }
}

// ---------- flat-view linear: rows of 128 consecutive floats, out = row @ lw.T + lb; IN-PLACE ----------
__global__ __launch_bounds__(256)
void viewlin_kernel(float* __restrict__ A, const float* __restrict__ lw,
                    const float* __restrict__ lb) {
    __shared__ __align__(16) float lwt[32 * 132];  // [c_local][o], stride 132
    __shared__ __align__(16) float ins[128 * 36];  // [c][r], stride 36
    const int tid = threadIdx.x;
    const long row0 = (long)blockIdx.x * 32;
    const int oq = tid & 31, rg = tid >> 5;
    const int o0 = oq * 4, r0 = rg * 4;
    for (int i = tid; i < 4096; i += 256) {
        int r = i >> 7, c = i & 127;
        long row = row0 + r;
        ins[c * 36 + r] = (row < 250000) ? A[row * 128 + c] : 0.f;
    }
    float acc[4][4] = {{0}};
#pragma unroll 1
    for (int cc = 0; cc < 4; ++cc) {
        const int c0 = cc * 32;
        __syncthreads();
        for (int i = tid; i < 4096; i += 256) {
            int o = i >> 5, c = i & 31;
            lwt[c * 132 + o] = lw[o * 128 + c0 + c];
        }
        __syncthreads();
#pragma unroll 1
        for (int c = 0; c < 32; ++c) {
            const float4 wv = *(const float4*)&lwt[c * 132 + o0];
            const float4 iv = *(const float4*)&ins[(c0 + c) * 36 + r0];
            const float wA[4] = {wv.x, wv.y, wv.z, wv.w};
            const float iA[4] = {iv.x, iv.y, iv.z, iv.w};
#pragma unroll
            for (int j = 0; j < 4; ++j)
#pragma unroll
                for (int i2 = 0; i2 < 4; ++i2)
                    acc[j][i2] = fmaf(wA[j], iA[i2], acc[j][i2]);
        }
    }
    float lbv[4];
#pragma unroll
    for (int j = 0; j < 4; ++j) lbv[j] = lb[o0 + j];
#pragma unroll
    for (int j = 0; j < 4; ++j)
#pragma unroll
        for (int i2 = 0; i2 < 4; ++i2) {
            long row = row0 + r0 + i2;
            if (row < 250000) A[row * 128 + o0 + j] = acc[j][i2] + lbv[j];
        }
}

// ---------- GroupNorm stats: per b, sum & sumsq over 8e6 contiguous floats ----------
__global__ void stats_kernel(const float* __restrict__ A, double* __restrict__ part) {
    __shared__ double ssum[256], ssq[256];
    const int blk = blockIdx.x;          // 0..1023, 256 per batch
    const int b = blk >> 8, sub = blk & 255;
    const long base = (long)b * 8000000 + (long)sub * 31250;
    double s = 0.0, q = 0.0;
    for (int i = threadIdx.x; i < 31250; i += 256) {
        float v = A[base + i];
        s += (double)v; q += (double)v * (double)v;
    }
    ssum[threadIdx.x] = s; ssq[threadIdx.x] = q;
    __syncthreads();
    for (int st = 128; st > 0; st >>= 1) {
        if (threadIdx.x < st) {
            ssum[threadIdx.x] += ssum[threadIdx.x + st];
            ssq[threadIdx.x]  += ssq[threadIdx.x + st];
        }
        __syncthreads();
    }
    if (threadIdx.x == 0) { part[blk * 2] = ssum[0]; part[blk * 2 + 1] = ssq[0]; }
}

__global__ void stats_final_kernel(const double* __restrict__ part, float* __restrict__ stats) {
    __shared__ double ssum[256], ssq[256];
    const int b = blockIdx.x;
    ssum[threadIdx.x] = part[(b * 256 + threadIdx.x) * 2];
    ssq[threadIdx.x]  = part[(b * 256 + threadIdx.x) * 2 + 1];
    __syncthreads();
    for (int st = 128; st > 0; st >>= 1) {
        if (threadIdx.x < st) {
            ssum[threadIdx.x] += ssum[threadIdx.x + st];
            ssq[threadIdx.x]  += ssq[threadIdx.x + st];
        }
        __syncthreads();
    }
    if (threadIdx.x == 0) {
        double mu = ssum[0] / 8000000.0;
        double var = ssq[0] / 8000000.0 - mu * mu;
        stats[b * 2] = (float)mu;
        stats[b * 2 + 1] = (float)(1.0 / sqrt(var + 1e-8));
    }
}

// ---------- intra finalize: transpose-back + GroupNorm affine + residual x -> d_out[B,N,K,S] ----------
__global__ void intra_fin_kernel(const float* __restrict__ f, const float* __restrict__ x,
                                 const float* __restrict__ stats, const float* __restrict__ gg,
                                 const float* __restrict__ gb, float* __restrict__ out) {
    __shared__ float tile[32][33];
    int kt = blockIdx.x, st = blockIdx.y;
    int bn = blockIdx.z; int b = bn >> 7, n = bn & 127;
    int tx = threadIdx.x & 31, ty = threadIdx.x >> 5;
    const float mu = stats[b * 2], rs = stats[b * 2 + 1];
    const float ga = gg[n] * rs, bb = gb[n];
    const float* fb = f + (long)(b * 250) * 32000 + n * 250;
#pragma unroll
    for (int j = 0; j < 4; ++j) {
        int k = kt * 32 + tx;
        int s = st * 32 + ty + j * 8;
        if (k < 250 && s < 250) tile[ty + j * 8][tx] = fb[(long)s * 32000 + k];
    }
    __syncthreads();
#pragma unroll
    for (int j = 0; j < 4; ++j) {
        int s = st * 32 + tx;
        int k = kt * 32 + ty + j * 8;
        if (k < 250 && s < 250) {
            long idx = ((long)(b * 128 + n) * 250 + k) * 250 + s;
            out[idx] = (tile[tx][ty + j * 8] - mu) * ga + bb + x[idx];
        }
    }
}

// ---------- inter input: B2[((b*250+k)*128+h)*250+s] = res[((b*128+h)*250+k)*250+s] ----------
__global__ void reorder_kernel(const float* __restrict__ res, float* __restrict__ B2) {
    long g = (long)blockIdx.x * 256 + threadIdx.x;
    if (g >= NTOT) return;
    int s = (int)(g % 250); long r = g / 250;
    int h = (int)(r % 128); long bk = r / 128;
    int k = (int)(bk % 250); int b = (int)(bk / 250);
    B2[g] = res[((long)(b * 128 + h) * 250 + k) * 250 + s];
}

// ---------- final: out += GroupNorm(inter) transposed back ----------
__global__ void final_kernel(const float* __restrict__ f2, const float* __restrict__ stats,
                             const float* __restrict__ gg, const float* __restrict__ gb,
                             float* __restrict__ out) {
    long g = (long)blockIdx.x * 256 + threadIdx.x;
    if (g >= NTOT) return;
    int s = (int)(g % 250); long r = g / 250;
    int k = (int)(r % 250); long bn = r / 250;
    int n = (int)(bn % 128); int b = (int)(bn / 128);
    float mu = stats[b * 2], rs = stats[b * 2 + 1];
    float v = f2[((long)(b * 250 + k) * 128 + n) * 250 + s];
    out[g] = (v - mu) * rs * gg[n] + gb[n] + out[g];
}

extern "C" void kernel_launch(void* const* d_in, const int* in_sizes, int n_in,
                              void* d_out, int out_size, void* d_ws, size_t ws_size,
                              hipStream_t stream) {
    (void)in_sizes; (void)n_in; (void)out_size; (void)ws_size;
    const float* x = (const float*)d_in[0];
    float* out = (float*)d_out;
    float* ws = (float*)d_ws;
    float* Abuf = ws;
    float* Bbuf = ws + (long)NTOT;
    float* wC   = ws + 2L * NTOT;                       // 16384 floats
    double* part = (double*)(ws + 2L * NTOT + 16384);   // 2048 doubles (8B aligned)
    float* stats = ws + 2L * NTOT + 16384 + 4096;       // 8 floats

    // intra params: 1..12; inter params: 13..24
    const float* i_logdt = (const float*)d_in[1];
    const float* i_logA  = (const float*)d_in[2];
    const float* i_Aim   = (const float*)d_in[3];
    const float* i_Cre   = (const float*)d_in[4];
    const float* i_Cim   = (const float*)d_in[5];
    const float* i_D     = (const float*)d_in[6];
    const float* i_ow    = (const float*)d_in[7];
    const float* i_ob    = (const float*)d_in[8];
    const float* i_lw    = (const float*)d_in[9];
    const float* i_lb    = (const float*)d_in[10];
    const float* i_gg    = (const float*)d_in[11];
    const float* i_gb    = (const float*)d_in[12];
    const float* e_logdt = (const float*)d_in[13];
    const float* e_logA  = (const float*)d_in[14];
    const float* e_Aim   = (const float*)d_in[15];
    const float* e_Cre   = (const float*)d_in[16];
    const float* e_Cim   = (const float*)d_in[17];
    const float* e_D     = (const float*)d_in[18];
    const float* e_ow    = (const float*)d_in[19];
    const float* e_ob    = (const float*)d_in[20];
    const float* e_lw    = (const float*)d_in[21];
    const float* e_lb    = (const float*)d_in[22];
    const float* e_gg    = (const float*)d_in[23];
    const float* e_gb    = (const float*)d_in[24];

    // ---- intra path ----
    transpose_in_kernel<<<dim3(8, 8, 512), 256, 0, stream>>>(x, Abuf);
    wc_kernel<<<16, 256, 0, stream>>>(i_logdt, i_logA, i_Aim, i_Cre, i_Cim, wC);
    conv_kernel<<<dim3(4, 128), 256, 0, stream>>>(Abuf, wC, i_D);
    outlin_kernel<<<dim3(8, 1000), 256, 0, stream>>>(Abuf, i_ow, i_ob);
    viewlin_kernel<<<7813, 256, 0, stream>>>(Abuf, i_lw, i_lb);
    stats_kernel<<<1024, 256, 0, stream>>>(Abuf, part);
    stats_final_kernel<<<4, 256, 0, stream>>>(part, stats);
    intra_fin_kernel<<<dim3(8, 8, 512), 256, 0, stream>>>(Abuf, x, stats, i_gg, i_gb, out);

    // ---- inter path ----
    reorder_kernel<<<NTOT / 256, 256, 0, stream>>>(out, Bbuf);
    wc_kernel<<<16, 256, 0, stream>>>(e_logdt, e_logA, e_Aim, e_Cre, e_Cim, wC);
    conv_kernel<<<dim3(4, 128), 256, 0, stream>>>(Bbuf, wC, e_D);
    outlin_kernel<<<dim3(8, 1000), 256, 0, stream>>>(Bbuf, e_ow, e_ob);
    viewlin_kernel<<<7813, 256, 0, stream>>>(Bbuf, e_lw, e_lb);
    stats_kernel<<<1024, 256, 0, stream>>>(Bbuf, part);
    stats_final_kernel<<<4, 256, 0, stream>>>(part, stats);
    final_kernel<<<NTOT / 256, 256, 0, stream>>>(Bbuf, stats, e_gg, e_gb, out);
}

// Round 2
// 2096.719 us; speedup vs baseline: 1.1180x; 1.1180x over previous
//
#include <hip/hip_runtime.h>
#include <math.h>

#define NTOT 32000000   // 4*128*250*250

__device__ __forceinline__ float fast_tanh(float t) {
    // tanh(t) = 1 - 2/(1+e^{2t})
    return 1.0f - 2.0f / (1.0f + __expf(2.0f * t));
}
__device__ __forceinline__ float gelu_f(float v) {
    return 0.5f * v * (1.0f + fast_tanh(0.7978845608028654f * (v + 0.044715f * v * v * v)));
}
__device__ __forceinline__ float sigmoid_f(float v) {
    return 1.0f / (1.0f + __expf(-v));
}

// ---------- S4D discretization: per (h,m): w = exp(dt*A), C2 = 2*C*(exp(dtA)-1)/A ----------
__global__ void wc_kernel(const float* __restrict__ log_dt, const float* __restrict__ logA_re,
                          const float* __restrict__ A_im, const float* __restrict__ C_re,
                          const float* __restrict__ C_im, float* __restrict__ wC) {
    int t = blockIdx.x * 256 + threadIdx.x;
    if (t >= 128 * 32) return;
    int h = t >> 5, m = t & 31;
    float dt  = expf(log_dt[h]);
    float are = -expf(logA_re[t]);
    float aim = A_im[t];
    float er  = expf(dt * are);
    float wr  = er * cosf(dt * aim);
    float wi  = er * sinf(dt * aim);
    float e1r = wr - 1.0f, e1i = wi;              // exp(dtA) - 1
    float inv = 1.0f / (are * are + aim * aim);
    float qr  = (e1r * are + e1i * aim) * inv;    // (exp(dtA)-1)/A
    float qi  = (e1i * are - e1r * aim) * inv;
    float cre = C_re[t], cim = C_im[t];
    wC[h * 128 + m]      = wr;
    wC[h * 128 + 32 + m] = wi;
    wC[h * 128 + 64 + m] = 2.0f * (cre * qr - cim * qi);
    wC[h * 128 + 96 + m] = 2.0f * (cre * qi + cim * qr);
}

// ---------- u[(b*250+s)*32000 + n*250 + k] = x[((b*128+n)*250+k)*250 + s] ----------
__global__ void transpose_in_kernel(const float* __restrict__ x, float* __restrict__ u) {
    __shared__ float tile[32][33];
    int kt = blockIdx.x, st = blockIdx.y;
    int bn = blockIdx.z; int b = bn >> 7, n = bn & 127;
    int tx = threadIdx.x & 31, ty = threadIdx.x >> 5;
    const float* xb = x + (long)((b * 128 + n) * 250) * 250;
    float* ub = u + (long)(b * 250) * 32000 + n * 250;
#pragma unroll
    for (int j = 0; j < 4; ++j) {
        int k = kt * 32 + ty + j * 8;
        int s = st * 32 + tx;
        if (k < 250 && s < 250) tile[ty + j * 8][tx] = xb[k * 250 + s];
    }
    __syncthreads();
#pragma unroll
    for (int j = 0; j < 4; ++j) {
        int k = kt * 32 + tx;
        int s = st * 32 + ty + j * 8;
        if (k < 250 && s < 250) ub[(long)s * 32000 + k] = tile[tx][ty + j * 8];
    }
}

// ---------- causal S4D conv via recurrence, + D*u, GELU; IN-PLACE on A [seq][h][l] ----------
// 2 lanes per (seq,h): lane half=0 handles modes 0..15, half=1 modes 16..31.
__global__ __launch_bounds__(256)
void conv_kernel(float* __restrict__ A, const float* __restrict__ wC,
                 const float* __restrict__ Dv) {
    __shared__ float su[128][17];
    const int tid = threadIdx.x;
    const int half = tid & 1;
    const int sq = tid >> 1;            // 0..127 local seq
    const int seq0 = blockIdx.x << 7;   // 8 tiles of 128 seqs (last partially OOB)
    const int h = blockIdx.y;
    const float* wc = wC + (h << 7) + half * 16;
    float wr[16], wi[16], cr[16], ci[16], sr[16], si[16];
#pragma unroll
    for (int m = 0; m < 16; ++m) {
        wr[m] = wc[m]; wi[m] = wc[32 + m]; cr[m] = wc[64 + m]; ci[m] = wc[96 + m];
        sr[m] = 0.0f; si[m] = 0.0f;
    }
    const float Dh = Dv[h];
    const int myseq = seq0 + sq;
#pragma unroll 1
    for (int lt = 0; lt < 16; ++lt) {
        const int l0 = lt << 4;
        const int len = (l0 + 16 <= 250) ? 16 : (250 - l0);
        __syncthreads();
#pragma unroll 1
        for (int i = tid; i < 2048; i += 256) {
            int rr = i >> 4, ll = i & 15;
            int seq = seq0 + rr;
            if (ll < len && seq < 1000)
                su[rr][ll] = A[(seq * 128 + h) * 250 + l0 + ll];
        }
        __syncthreads();
#pragma unroll 1
        for (int jj = 0; jj < len; ++jj) {
            const float u = su[sq][jj];
            float a[4] = {0.f, 0.f, 0.f, 0.f};
#pragma unroll
            for (int m = 0; m < 16; ++m) {
                float nr = fmaf(wr[m], sr[m], fmaf(-wi[m], si[m], u));
                float ni = fmaf(wr[m], si[m], wi[m] * sr[m]);
                sr[m] = nr; si[m] = ni;
                a[m & 3] = fmaf(cr[m], nr, fmaf(-ci[m], ni, a[m & 3]));
            }
            float yh = (a[0] + a[1]) + (a[2] + a[3]);
            float y = yh + __shfl_xor(yh, 1) + Dh * u;
            float g = gelu_f(y);
            if (half == 0) su[sq][jj] = g;
        }
        __syncthreads();
#pragma unroll 1
        for (int i = tid; i < 2048; i += 256) {
            int rr = i >> 4, ll = i & 15;
            int seq = seq0 + rr;
            if (ll < len && seq < 1000)
                A[(seq * 128 + h) * 250 + l0 + ll] = su[rr][ll];
        }
    }
    (void)myseq;
}

// ---------- out-linear 128->256 + GLU -> 128; IN-PLACE on A [seq][h][l] ----------
// block: 256o x 64l for one seq; thread: o0=(tid&31)*4 (plus o0+128), l0=(tid>>5)*8
__global__ __launch_bounds__(256)
void outlin_kernel(float* __restrict__ A, const float* __restrict__ ow,
                   const float* __restrict__ ob) {
    __shared__ __align__(16) float Us[128][64];    // 32 KB
    __shared__ __align__(16) float Ws[32][260];    // 33.3 KB
    const int tid = threadIdx.x;
    const int seq = blockIdx.y;
    const int l0g = blockIdx.x * 64;
    const int oq = tid & 31, lg = tid >> 5;
    const int o0 = oq * 4;
    const int l0 = lg * 8;
    for (int i = tid; i < 8192; i += 256) {
        int hh = i >> 6, ll = i & 63;
        int l = l0g + ll;
        Us[hh][ll] = (l < 250) ? A[(seq * 128 + hh) * 250 + l] : 0.f;
    }
    float accA[4][8] = {{0}}, accB[4][8] = {{0}};
#pragma unroll 1
    for (int hc = 0; hc < 4; ++hc) {
        const int h0 = hc * 32;
        __syncthreads();
        for (int i = tid; i < 8192; i += 256) {
            int o = i >> 5, hh = i & 31;
            Ws[hh][o] = ow[o * 128 + h0 + hh];
        }
        __syncthreads();
#pragma unroll 2
        for (int hh = 0; hh < 32; ++hh) {
            const float4 wa = *(const float4*)&Ws[hh][o0];
            const float4 wb = *(const float4*)&Ws[hh][128 + o0];
            const float4 u0 = *(const float4*)&Us[h0 + hh][l0];
            const float4 u1 = *(const float4*)&Us[h0 + hh][l0 + 4];
            const float wA[4] = {wa.x, wa.y, wa.z, wa.w};
            const float wB[4] = {wb.x, wb.y, wb.z, wb.w};
            const float uu[8] = {u0.x, u0.y, u0.z, u0.w, u1.x, u1.y, u1.z, u1.w};
#pragma unroll
            for (int j = 0; j < 4; ++j)
#pragma unroll
                for (int i2 = 0; i2 < 8; ++i2) {
                    accA[j][i2] = fmaf(wA[j], uu[i2], accA[j][i2]);
                    accB[j][i2] = fmaf(wB[j], uu[i2], accB[j][i2]);
                }
        }
    }
#pragma unroll
    for (int j = 0; j < 4; ++j) {
        const float b1 = ob[o0 + j], b2 = ob[128 + o0 + j];
#pragma unroll
        for (int i2 = 0; i2 < 8; ++i2) {
            int l = l0g + l0 + i2;
            if (l < 250) {
                float z1 = accA[j][i2] + b1;
                float z2 = accB[j][i2] + b2;
                A[(seq * 128 + o0 + j) * 250 + l] = z1 * sigmoid_f(z2);
            }
        }
    }
}

// ---------- flat-view linear: rows of 128 consecutive floats, out = row @ lw.T + lb; IN-PLACE ----------
// block: 128o x 128rows; thread: o0=(tid&31)*4, r0=(tid>>5)*16
__global__ __launch_bounds__(256)
void viewlin_kernel(float* __restrict__ A, const float* __restrict__ lw,
                    const float* __restrict__ lb) {
    __shared__ __align__(16) float ins[32][132];   // [c][r]
    __shared__ __align__(16) float lws[32][132];   // [c][o]
    const int tid = threadIdx.x;
    const long row0 = (long)blockIdx.x * 128;
    const int oq = tid & 31, rg = tid >> 5;
    const int o0 = oq * 4, r0 = rg * 16;
    float acc[4][16] = {{0}};
#pragma unroll 1
    for (int cc = 0; cc < 4; ++cc) {
        const int c0 = cc * 32;
        __syncthreads();
        for (int i = tid; i < 4096; i += 256) {
            int r = i >> 5, c = i & 31;
            long row = row0 + r;
            ins[c][r] = (row < 250000) ? A[row * 128 + c0 + c] : 0.f;
        }
        for (int i = tid; i < 4096; i += 256) {
            int o = i >> 5, c = i & 31;
            lws[c][o] = lw[o * 128 + c0 + c];
        }
        __syncthreads();
#pragma unroll 2
        for (int c = 0; c < 32; ++c) {
            const float4 wv = *(const float4*)&lws[c][o0];
            const float4 i0 = *(const float4*)&ins[c][r0];
            const float4 i1 = *(const float4*)&ins[c][r0 + 4];
            const float4 i2 = *(const float4*)&ins[c][r0 + 8];
            const float4 i3 = *(const float4*)&ins[c][r0 + 12];
            const float wA[4] = {wv.x, wv.y, wv.z, wv.w};
            const float iA[16] = {i0.x, i0.y, i0.z, i0.w, i1.x, i1.y, i1.z, i1.w,
                                  i2.x, i2.y, i2.z, i2.w, i3.x, i3.y, i3.z, i3.w};
#pragma unroll
            for (int j = 0; j < 4; ++j)
#pragma unroll
                for (int k = 0; k < 16; ++k)
                    acc[j][k] = fmaf(wA[j], iA[k], acc[j][k]);
        }
    }
    const float b0 = lb[o0], b1 = lb[o0 + 1], b2 = lb[o0 + 2], b3 = lb[o0 + 3];
#pragma unroll
    for (int k = 0; k < 16; ++k) {
        long row = row0 + r0 + k;
        if (row < 250000) {
            float4 v;
            v.x = acc[0][k] + b0; v.y = acc[1][k] + b1;
            v.z = acc[2][k] + b2; v.w = acc[3][k] + b3;
            *(float4*)&A[row * 128 + o0] = v;
        }
    }
}

// ---------- GroupNorm stats: per b, sum & sumsq over 8e6 contiguous floats ----------
__global__ void stats_kernel(const float* __restrict__ A, double* __restrict__ part) {
    __shared__ double ssum[256], ssq[256];
    const int blk = blockIdx.x;          // 0..1023, 256 per batch
    const int b = blk >> 8, sub = blk & 255;
    const long base = (long)b * 8000000 + (long)sub * 31250;
    double s = 0.0, q = 0.0;
    for (int i = threadIdx.x; i < 31250; i += 256) {
        float v = A[base + i];
        s += (double)v; q += (double)v * (double)v;
    }
    ssum[threadIdx.x] = s; ssq[threadIdx.x] = q;
    __syncthreads();
    for (int st = 128; st > 0; st >>= 1) {
        if (threadIdx.x < st) {
            ssum[threadIdx.x] += ssum[threadIdx.x + st];
            ssq[threadIdx.x]  += ssq[threadIdx.x + st];
        }
        __syncthreads();
    }
    if (threadIdx.x == 0) { part[blk * 2] = ssum[0]; part[blk * 2 + 1] = ssq[0]; }
}

__global__ void stats_final_kernel(const double* __restrict__ part, float* __restrict__ stats) {
    __shared__ double ssum[256], ssq[256];
    const int b = blockIdx.x;
    ssum[threadIdx.x] = part[(b * 256 + threadIdx.x) * 2];
    ssq[threadIdx.x]  = part[(b * 256 + threadIdx.x) * 2 + 1];
    __syncthreads();
    for (int st = 128; st > 0; st >>= 1) {
        if (threadIdx.x < st) {
            ssum[threadIdx.x] += ssum[threadIdx.x + st];
            ssq[threadIdx.x]  += ssq[threadIdx.x + st];
        }
        __syncthreads();
    }
    if (threadIdx.x == 0) {
        double mu = ssum[0] / 8000000.0;
        double var = ssq[0] / 8000000.0 - mu * mu;
        stats[b * 2] = (float)mu;
        stats[b * 2 + 1] = (float)(1.0 / sqrt(var + 1e-8));
    }
}

// ---------- intra finalize: transpose-back + GroupNorm affine + residual x -> d_out[B,N,K,S] ----------
__global__ void intra_fin_kernel(const float* __restrict__ f, const float* __restrict__ x,
                                 const float* __restrict__ stats, const float* __restrict__ gg,
                                 const float* __restrict__ gb, float* __restrict__ out) {
    __shared__ float tile[32][33];
    int kt = blockIdx.x, st = blockIdx.y;
    int bn = blockIdx.z; int b = bn >> 7, n = bn & 127;
    int tx = threadIdx.x & 31, ty = threadIdx.x >> 5;
    const float mu = stats[b * 2], rs = stats[b * 2 + 1];
    const float ga = gg[n] * rs, bb = gb[n];
    const float* fb = f + (long)(b * 250) * 32000 + n * 250;
#pragma unroll
    for (int j = 0; j < 4; ++j) {
        int k = kt * 32 + tx;
        int s = st * 32 + ty + j * 8;
        if (k < 250 && s < 250) tile[ty + j * 8][tx] = fb[(long)s * 32000 + k];
    }
    __syncthreads();
#pragma unroll
    for (int j = 0; j < 4; ++j) {
        int s = st * 32 + tx;
        int k = kt * 32 + ty + j * 8;
        if (k < 250 && s < 250) {
            long idx = ((long)(b * 128 + n) * 250 + k) * 250 + s;
            out[idx] = (tile[tx][ty + j * 8] - mu) * ga + bb + x[idx];
        }
    }
}

// ---------- inter input: B2[((b*250+k)*128+h)*250+s] = res[((b*128+h)*250+k)*250+s] ----------
__global__ void reorder_kernel(const float* __restrict__ res, float* __restrict__ B2) {
    long g = (long)blockIdx.x * 256 + threadIdx.x;
    if (g >= NTOT) return;
    int s = (int)(g % 250); long r = g / 250;
    int h = (int)(r % 128); long bk = r / 128;
    int k = (int)(bk % 250); int b = (int)(bk / 250);
    B2[g] = res[((long)(b * 128 + h) * 250 + k) * 250 + s];
}

// ---------- final: out += GroupNorm(inter) transposed back ----------
__global__ void final_kernel(const float* __restrict__ f2, const float* __restrict__ stats,
                             const float* __restrict__ gg, const float* __restrict__ gb,
                             float* __restrict__ out) {
    long g = (long)blockIdx.x * 256 + threadIdx.x;
    if (g >= NTOT) return;
    int s = (int)(g % 250); long r = g / 250;
    int k = (int)(r % 250); long bn = r / 250;
    int n = (int)(bn % 128); int b = (int)(bn / 128);
    float mu = stats[b * 2], rs = stats[b * 2 + 1];
    float v = f2[((long)(b * 250 + k) * 128 + n) * 250 + s];
    out[g] = (v - mu) * rs * gg[n] + gb[n] + out[g];
}

extern "C" void kernel_launch(void* const* d_in, const int* in_sizes, int n_in,
                              void* d_out, int out_size, void* d_ws, size_t ws_size,
                              hipStream_t stream) {
    (void)in_sizes; (void)n_in; (void)out_size; (void)ws_size;
    const float* x = (const float*)d_in[0];
    float* out = (float*)d_out;
    float* ws = (float*)d_ws;
    float* Abuf = ws;
    float* Bbuf = ws + (long)NTOT;
    float* wC   = ws + 2L * NTOT;                       // 16384 floats
    double* part = (double*)(ws + 2L * NTOT + 16384);   // 2048 doubles
    float* stats = ws + 2L * NTOT + 16384 + 4096;       // 8 floats

    const float* i_logdt = (const float*)d_in[1];
    const float* i_logA  = (const float*)d_in[2];
    const float* i_Aim   = (const float*)d_in[3];
    const float* i_Cre   = (const float*)d_in[4];
    const float* i_Cim   = (const float*)d_in[5];
    const float* i_D     = (const float*)d_in[6];
    const float* i_ow    = (const float*)d_in[7];
    const float* i_ob    = (const float*)d_in[8];
    const float* i_lw    = (const float*)d_in[9];
    const float* i_lb    = (const float*)d_in[10];
    const float* i_gg    = (const float*)d_in[11];
    const float* i_gb    = (const float*)d_in[12];
    const float* e_logdt = (const float*)d_in[13];
    const float* e_logA  = (const float*)d_in[14];
    const float* e_Aim   = (const float*)d_in[15];
    const float* e_Cre   = (const float*)d_in[16];
    const float* e_Cim   = (const float*)d_in[17];
    const float* e_D     = (const float*)d_in[18];
    const float* e_ow    = (const float*)d_in[19];
    const float* e_ob    = (const float*)d_in[20];
    const float* e_lw    = (const float*)d_in[21];
    const float* e_lb    = (const float*)d_in[22];
    const float* e_gg    = (const float*)d_in[23];
    const float* e_gb    = (const float*)d_in[24];

    // ---- intra path ----
    transpose_in_kernel<<<dim3(8, 8, 512), 256, 0, stream>>>(x, Abuf);
    wc_kernel<<<16, 256, 0, stream>>>(i_logdt, i_logA, i_Aim, i_Cre, i_Cim, wC);
    conv_kernel<<<dim3(8, 128), 256, 0, stream>>>(Abuf, wC, i_D);
    outlin_kernel<<<dim3(4, 1000), 256, 0, stream>>>(Abuf, i_ow, i_ob);
    viewlin_kernel<<<1954, 256, 0, stream>>>(Abuf, i_lw, i_lb);
    stats_kernel<<<1024, 256, 0, stream>>>(Abuf, part);
    stats_final_kernel<<<4, 256, 0, stream>>>(part, stats);
    intra_fin_kernel<<<dim3(8, 8, 512), 256, 0, stream>>>(Abuf, x, stats, i_gg, i_gb, out);

    // ---- inter path ----
    reorder_kernel<<<NTOT / 256, 256, 0, stream>>>(out, Bbuf);
    wc_kernel<<<16, 256, 0, stream>>>(e_logdt, e_logA, e_Aim, e_Cre, e_Cim, wC);
    conv_kernel<<<dim3(8, 128), 256, 0, stream>>>(Bbuf, wC, e_D);
    outlin_kernel<<<dim3(4, 1000), 256, 0, stream>>>(Bbuf, e_ow, e_ob);
    viewlin_kernel<<<1954, 256, 0, stream>>>(Bbuf, e_lw, e_lb);
    stats_kernel<<<1024, 256, 0, stream>>>(Bbuf, part);
    stats_final_kernel<<<4, 256, 0, stream>>>(part, stats);
    final_kernel<<<NTOT / 256, 256, 0, stream>>>(Bbuf, stats, e_gg, e_gb, out);
}

// Round 3
// 1533.081 us; speedup vs baseline: 1.5290x; 1.3677x over previous
//
#include <hip/hip_runtime.h>
#include <math.h>

#define NTOT 32000000   // 4*128*250*250

typedef __attribute__((ext_vector_type(8))) short bf8_t;   // 8 bf16 (4 VGPRs)
typedef __attribute__((ext_vector_type(4))) float f4_t;    // MFMA accumulator

__device__ __forceinline__ float fast_tanh(float t) {
    return 1.0f - 2.0f / (1.0f + __expf(2.0f * t));
}
__device__ __forceinline__ float gelu_f(float v) {
    return 0.5f * v * (1.0f + fast_tanh(0.7978845608028654f * (v + 0.044715f * v * v * v)));
}
__device__ __forceinline__ float sigmoid_f(float v) {
    return 1.0f / (1.0f + __expf(-v));
}
__device__ __forceinline__ unsigned short f2bf(float f) {
    unsigned u = __float_as_uint(f);
    u = (u + 0x7FFFu + ((u >> 16) & 1u)) >> 16;
    return (unsigned short)u;
}

// ---------- S4D discretization ----------
__global__ void wc_kernel(const float* __restrict__ log_dt, const float* __restrict__ logA_re,
                          const float* __restrict__ A_im, const float* __restrict__ C_re,
                          const float* __restrict__ C_im, float* __restrict__ wC) {
    int t = blockIdx.x * 256 + threadIdx.x;
    if (t >= 128 * 32) return;
    int h = t >> 5, m = t & 31;
    float dt  = expf(log_dt[h]);
    float are = -expf(logA_re[t]);
    float aim = A_im[t];
    float er  = expf(dt * are);
    float wr  = er * cosf(dt * aim);
    float wi  = er * sinf(dt * aim);
    float e1r = wr - 1.0f, e1i = wi;
    float inv = 1.0f / (are * are + aim * aim);
    float qr  = (e1r * are + e1i * aim) * inv;
    float qi  = (e1i * are - e1r * aim) * inv;
    float cre = C_re[t], cim = C_im[t];
    wC[h * 128 + m]      = wr;
    wC[h * 128 + 32 + m] = wi;
    wC[h * 128 + 64 + m] = 2.0f * (cre * qr - cim * qi);
    wC[h * 128 + 96 + m] = 2.0f * (cre * qi + cim * qr);
}

// ---------- weight fp32 -> bf16 ----------
__global__ void cvtw_kernel(const float* __restrict__ ow, const float* __restrict__ lw,
                            unsigned short* __restrict__ owbf, unsigned short* __restrict__ lwbf) {
    int t = blockIdx.x * 256 + threadIdx.x;
    if (t < 32768) owbf[t] = f2bf(ow[t]);
    else if (t < 49152) lwbf[t - 32768] = f2bf(lw[t - 32768]);
}

// ---------- causal S4D conv via recurrence, + D*u, GELU -> bf16 Y [seq][h][l(250)] ----------
// inter==0: in = x [b,h,K,S], time=k (stride 250), pos=s (contig); seq=b*250+s
// inter==1: in = out [b,h,K,S], time=s (contig), pos=k (stride 250); seq=b*250+k
// block: x = pos-half (125 each), y = h, z = b. 2 lanes per seq (16 modes each).
__global__ __launch_bounds__(256)
void conv_kernel(const float* __restrict__ in, unsigned short* __restrict__ Y,
                 const float* __restrict__ wC, const float* __restrict__ Dv, int inter) {
    __shared__ float su[128][34];
    const int tid = threadIdx.x;
    const int half = tid & 1;
    const int sq = tid >> 1;          // local pos 0..127 (active <125)
    const int h = blockIdx.y, b = blockIdx.z;
    const int p0 = blockIdx.x * 125;
    const float* wc = wC + (h << 7) + half * 16;
    float wr[16], wi[16], cr[16], ci[16], sr[16], si[16];
#pragma unroll
    for (int m = 0; m < 16; ++m) {
        wr[m] = wc[m]; wi[m] = wc[32 + m]; cr[m] = wc[64 + m]; ci[m] = wc[96 + m];
        sr[m] = 0.0f; si[m] = 0.0f;
    }
    const float Dh = Dv[h];
    const float* bh = in + (long)((b * 128 + h) * 250) * 250;
    unsigned short* Yb = Y + ((long)(b * 250 + p0) * 128 + h) * 250;
#pragma unroll 1
    for (int lt = 0; lt < 8; ++lt) {
        const int l0 = lt << 5;
        const int len = (l0 + 32 <= 250) ? 32 : (250 - l0);
        __syncthreads();
        if (!inter) {
#pragma unroll 1
            for (int i = tid; i < 4096; i += 256) {
                int ll = i >> 7, pp = i & 127;
                if (ll < len && pp < 125)
                    su[pp][ll] = bh[(long)(l0 + ll) * 250 + p0 + pp];
            }
        } else {
#pragma unroll 1
            for (int i = tid; i < 4096; i += 256) {
                int pp = i >> 5, ll = i & 31;
                if (ll < len && pp < 125)
                    su[pp][ll] = bh[(long)(p0 + pp) * 250 + l0 + ll];
            }
        }
        __syncthreads();
#pragma unroll 1
        for (int jj = 0; jj < len; ++jj) {
            const float u = su[sq][jj];
            float a[4] = {0.f, 0.f, 0.f, 0.f};
#pragma unroll
            for (int m = 0; m < 16; ++m) {
                float nr = fmaf(wr[m], sr[m], fmaf(-wi[m], si[m], u));
                float ni = fmaf(wr[m], si[m], wi[m] * sr[m]);
                sr[m] = nr; si[m] = ni;
                a[m & 3] = fmaf(cr[m], nr, fmaf(-ci[m], ni, a[m & 3]));
            }
            float yh = (a[0] + a[1]) + (a[2] + a[3]);
            float y = yh + __shfl_xor(yh, 1) + Dh * u;
            if (half == 0 && sq < 125) su[sq][jj] = gelu_f(y);
        }
        __syncthreads();
#pragma unroll 1
        for (int i = tid; i < 4096; i += 256) {
            int pp = i >> 5, ll = i & 31;
            if (ll < len && pp < 125)
                Yb[(long)pp * 32000 + l0 + ll] = f2bf(su[pp][ll]);
        }
    }
}

// ---------- out-linear 128->256 (bf16 MFMA) + GLU -> bf16 G [seq][h][l(250)] ----------
// block: one seq, 64 l; 4 waves, wave w owns o-tiles {2w,2w+1,2w+8,2w+9} (GLU pairs in-wave)
__global__ __launch_bounds__(256)
void outlin_kernel(const unsigned short* __restrict__ Ybf, const unsigned short* __restrict__ owbf,
                   const float* __restrict__ ob, unsigned short* __restrict__ Gbf) {
    __shared__ unsigned short Yl[64 * 136];   // [l][h], pitch 136
    const int tid = threadIdx.x;
    const int lane = tid & 63, wave = tid >> 6;
    const int lid = lane & 15, quad = lane >> 4;
    const int l0g = blockIdx.x * 64;
    const int seq = blockIdx.y;
    const unsigned short* Ys = Ybf + (long)seq * 32000;
    // stage Y tile transposed: [h][l] -> LDS [l][h]
#pragma unroll 1
    for (int i = tid; i < 4096; i += 256) {
        int h = i >> 5, l2 = (i & 31) * 2;
        int l = l0g + l2;
        unsigned int v = 0;
        if (l < 250) v = *(const unsigned int*)(Ys + h * 250 + l);
        Yl[l2 * 136 + h] = (unsigned short)(v & 0xFFFF);
        Yl[(l2 + 1) * 136 + h] = (unsigned short)(v >> 16);
    }
    const int tb0 = 2 * wave;
    int tmap[4] = {tb0, tb0 + 1, tb0 + 8, tb0 + 9};
    bf8_t wf[4][4];   // [kchunk][tile]
#pragma unroll
    for (int c = 0; c < 4; ++c)
#pragma unroll
        for (int t = 0; t < 4; ++t)
            wf[c][t] = *(const bf8_t*)(owbf + (tmap[t] * 16 + lid) * 128 + c * 32 + quad * 8);
    __syncthreads();
    f4_t acc[4][4];   // [tile][ntile]
#pragma unroll
    for (int t = 0; t < 4; ++t)
#pragma unroll
        for (int j = 0; j < 4; ++j)
            acc[t][j] = (f4_t)0.0f;
#pragma unroll 1
    for (int c = 0; c < 4; ++c) {
        bf8_t bfr[4];
#pragma unroll
        for (int j = 0; j < 4; ++j)
            bfr[j] = *(const bf8_t*)(Yl + (j * 16 + lid) * 136 + c * 32 + quad * 8);
#pragma unroll
        for (int t = 0; t < 4; ++t)
#pragma unroll
            for (int j = 0; j < 4; ++j)
                acc[t][j] = __builtin_amdgcn_mfma_f32_16x16x32_bf16(wf[c][t], bfr[j], acc[t][j], 0, 0, 0);
    }
    // GLU epilogue: z1 = tiles tmap[0..1], z2 = tiles tmap[2..3] (= +128 channels)
#pragma unroll
    for (int p = 0; p < 2; ++p) {
        int ob0 = tmap[p] * 16 + quad * 4;
#pragma unroll
        for (int reg = 0; reg < 4; ++reg) {
            int o = ob0 + reg;
            float b1 = ob[o], b2 = ob[128 + o];
            unsigned short* Gr = Gbf + ((long)seq * 128 + o) * 250;
#pragma unroll
            for (int j = 0; j < 4; ++j) {
                int l = l0g + j * 16 + lid;
                if (l < 250) {
                    float z1 = acc[p][j][reg] + b1;
                    float z2 = acc[p + 2][j][reg] + b2;
                    Gr[l] = f2bf(z1 * sigmoid_f(z2));
                }
            }
        }
    }
}

// ---------- flat-view linear (bf16 MFMA): V[r][o] = G[r][c] @ lw^T + lb, r<250000 ----------
// block: 128 rows (4 waves x 32), full N=128; A-frags direct from global, B from L1
__global__ __launch_bounds__(256)
void viewlin_kernel(const unsigned short* __restrict__ Gbf, const unsigned short* __restrict__ lwbf,
                    const float* __restrict__ lb, float* __restrict__ V) {
    const int tid = threadIdx.x;
    const int lane = tid & 63, wave = tid >> 6;
    const int lid = lane & 15, quad = lane >> 4;
    const long r0 = (long)blockIdx.x * 128 + wave * 32;
    f4_t acc[2][8];
#pragma unroll
    for (int mt = 0; mt < 2; ++mt)
#pragma unroll
        for (int nt = 0; nt < 8; ++nt)
            acc[mt][nt] = (f4_t)0.0f;
#pragma unroll 1
    for (int c = 0; c < 4; ++c) {
        bf8_t af[2];
#pragma unroll
        for (int mt = 0; mt < 2; ++mt) {
            long r = r0 + mt * 16 + lid;
            if (r > 249999) r = 249999;
            af[mt] = *(const bf8_t*)(Gbf + r * 128 + c * 32 + quad * 8);
        }
#pragma unroll
        for (int nt = 0; nt < 8; ++nt) {
            bf8_t bfr = *(const bf8_t*)(lwbf + (nt * 16 + lid) * 128 + c * 32 + quad * 8);
            acc[0][nt] = __builtin_amdgcn_mfma_f32_16x16x32_bf16(af[0], bfr, acc[0][nt], 0, 0, 0);
            acc[1][nt] = __builtin_amdgcn_mfma_f32_16x16x32_bf16(af[1], bfr, acc[1][nt], 0, 0, 0);
        }
    }
#pragma unroll
    for (int nt = 0; nt < 8; ++nt) {
        int o = nt * 16 + lid;
        float bb = lb[o];
#pragma unroll
        for (int mt = 0; mt < 2; ++mt)
#pragma unroll
            for (int reg = 0; reg < 4; ++reg) {
                long r = r0 + mt * 16 + quad * 4 + reg;
                if (r < 250000) V[r * 128 + o] = acc[mt][nt][reg] + bb;
            }
    }
}

// ---------- GroupNorm stats ----------
__global__ void stats_kernel(const float* __restrict__ A, double* __restrict__ part) {
    __shared__ double ssum[256], ssq[256];
    const int blk = blockIdx.x;
    const int b = blk >> 8, sub = blk & 255;
    const long base = (long)b * 8000000 + (long)sub * 31250;
    double s = 0.0, q = 0.0;
    for (int i = threadIdx.x; i < 31250; i += 256) {
        float v = A[base + i];
        s += (double)v; q += (double)v * (double)v;
    }
    ssum[threadIdx.x] = s; ssq[threadIdx.x] = q;
    __syncthreads();
    for (int st = 128; st > 0; st >>= 1) {
        if (threadIdx.x < st) {
            ssum[threadIdx.x] += ssum[threadIdx.x + st];
            ssq[threadIdx.x]  += ssq[threadIdx.x + st];
        }
        __syncthreads();
    }
    if (threadIdx.x == 0) { part[blk * 2] = ssum[0]; part[blk * 2 + 1] = ssq[0]; }
}

__global__ void stats_final_kernel(const double* __restrict__ part, float* __restrict__ stats) {
    __shared__ double ssum[256], ssq[256];
    const int b = blockIdx.x;
    ssum[threadIdx.x] = part[(b * 256 + threadIdx.x) * 2];
    ssq[threadIdx.x]  = part[(b * 256 + threadIdx.x) * 2 + 1];
    __syncthreads();
    for (int st = 128; st > 0; st >>= 1) {
        if (threadIdx.x < st) {
            ssum[threadIdx.x] += ssum[threadIdx.x + st];
            ssq[threadIdx.x]  += ssq[threadIdx.x + st];
        }
        __syncthreads();
    }
    if (threadIdx.x == 0) {
        double mu = ssum[0] / 8000000.0;
        double var = ssq[0] / 8000000.0 - mu * mu;
        stats[b * 2] = (float)mu;
        stats[b * 2 + 1] = (float)(1.0 / sqrt(var + 1e-8));
    }
}

// ---------- intra finalize: transpose-back + GN affine + residual x -> out[B,N,K,S] ----------
__global__ void intra_fin_kernel(const float* __restrict__ f, const float* __restrict__ x,
                                 const float* __restrict__ stats, const float* __restrict__ gg,
                                 const float* __restrict__ gb, float* __restrict__ out) {
    __shared__ float tile[32][33];
    int kt = blockIdx.x, st = blockIdx.y;
    int bn = blockIdx.z; int b = bn >> 7, n = bn & 127;
    int tx = threadIdx.x & 31, ty = threadIdx.x >> 5;
    const float mu = stats[b * 2], rs = stats[b * 2 + 1];
    const float ga = gg[n] * rs, bb = gb[n];
    const float* fb = f + (long)(b * 250) * 32000 + n * 250;
#pragma unroll
    for (int j = 0; j < 4; ++j) {
        int k = kt * 32 + tx;
        int s = st * 32 + ty + j * 8;
        if (k < 250 && s < 250) tile[ty + j * 8][tx] = fb[(long)s * 32000 + k];
    }
    __syncthreads();
#pragma unroll
    for (int j = 0; j < 4; ++j) {
        int s = st * 32 + tx;
        int k = kt * 32 + ty + j * 8;
        if (k < 250 && s < 250) {
            long idx = ((long)(b * 128 + n) * 250 + k) * 250 + s;
            out[idx] = (tile[tx][ty + j * 8] - mu) * ga + bb + x[idx];
        }
    }
}

// ---------- final: out += GroupNorm(inter) transposed back ----------
__global__ void final_kernel(const float* __restrict__ f2, const float* __restrict__ stats,
                             const float* __restrict__ gg, const float* __restrict__ gb,
                             float* __restrict__ out) {
    long g = (long)blockIdx.x * 256 + threadIdx.x;
    if (g >= NTOT) return;
    int s = (int)(g % 250); long r = g / 250;
    int k = (int)(r % 250); long bn = r / 250;
    int n = (int)(bn % 128); int b = (int)(bn / 128);
    float mu = stats[b * 2], rs = stats[b * 2 + 1];
    float v = f2[((long)(b * 250 + k) * 128 + n) * 250 + s];
    out[g] = (v - mu) * rs * gg[n] + gb[n] + out[g];
}

extern "C" void kernel_launch(void* const* d_in, const int* in_sizes, int n_in,
                              void* d_out, int out_size, void* d_ws, size_t ws_size,
                              hipStream_t stream) {
    (void)in_sizes; (void)n_in; (void)out_size; (void)ws_size;
    const float* x = (const float*)d_in[0];
    float* out = (float*)d_out;
    char* base = (char*)d_ws;
    float* V            = (float*)base;                              // 128,000,000 B
    unsigned short* Ybf = (unsigned short*)(base + 128000000L);      //  64,000,000 B
    unsigned short* Gbf = (unsigned short*)(base + 192000000L);      //  64,000,000 B
    float* wC           = (float*)(base + 256000000L);               //      65,536 B
    unsigned short* owbf= (unsigned short*)(base + 256065536L);      //      65,536 B
    unsigned short* lwbf= (unsigned short*)(base + 256131072L);      //      32,768 B
    double* part        = (double*)(base + 256163840L);              //      16,384 B
    float* stats        = (float*)(base + 256180224L);               //          32 B

    const float* i_logdt = (const float*)d_in[1];
    const float* i_logA  = (const float*)d_in[2];
    const float* i_Aim   = (const float*)d_in[3];
    const float* i_Cre   = (const float*)d_in[4];
    const float* i_Cim   = (const float*)d_in[5];
    const float* i_D     = (const float*)d_in[6];
    const float* i_ow    = (const float*)d_in[7];
    const float* i_ob    = (const float*)d_in[8];
    const float* i_lw    = (const float*)d_in[9];
    const float* i_lb    = (const float*)d_in[10];
    const float* i_gg    = (const float*)d_in[11];
    const float* i_gb    = (const float*)d_in[12];
    const float* e_logdt = (const float*)d_in[13];
    const float* e_logA  = (const float*)d_in[14];
    const float* e_Aim   = (const float*)d_in[15];
    const float* e_Cre   = (const float*)d_in[16];
    const float* e_Cim   = (const float*)d_in[17];
    const float* e_D     = (const float*)d_in[18];
    const float* e_ow    = (const float*)d_in[19];
    const float* e_ob    = (const float*)d_in[20];
    const float* e_lw    = (const float*)d_in[21];
    const float* e_lb    = (const float*)d_in[22];
    const float* e_gg    = (const float*)d_in[23];
    const float* e_gb    = (const float*)d_in[24];

    // ---- intra path ----
    wc_kernel<<<16, 256, 0, stream>>>(i_logdt, i_logA, i_Aim, i_Cre, i_Cim, wC);
    cvtw_kernel<<<192, 256, 0, stream>>>(i_ow, i_lw, owbf, lwbf);
    conv_kernel<<<dim3(2, 128, 4), 256, 0, stream>>>(x, Ybf, wC, i_D, 0);
    outlin_kernel<<<dim3(4, 1000), 256, 0, stream>>>(Ybf, owbf, i_ob, Gbf);
    viewlin_kernel<<<1954, 256, 0, stream>>>(Gbf, lwbf, i_lb, V);
    stats_kernel<<<1024, 256, 0, stream>>>(V, part);
    stats_final_kernel<<<4, 256, 0, stream>>>(part, stats);
    intra_fin_kernel<<<dim3(8, 8, 512), 256, 0, stream>>>(V, x, stats, i_gg, i_gb, out);

    // ---- inter path ----
    wc_kernel<<<16, 256, 0, stream>>>(e_logdt, e_logA, e_Aim, e_Cre, e_Cim, wC);
    cvtw_kernel<<<192, 256, 0, stream>>>(e_ow, e_lw, owbf, lwbf);
    conv_kernel<<<dim3(2, 128, 4), 256, 0, stream>>>(out, Ybf, wC, e_D, 1);
    outlin_kernel<<<dim3(4, 1000), 256, 0, stream>>>(Ybf, owbf, e_ob, Gbf);
    viewlin_kernel<<<1954, 256, 0, stream>>>(Gbf, lwbf, e_lb, V);
    stats_kernel<<<1024, 256, 0, stream>>>(V, part);
    stats_final_kernel<<<4, 256, 0, stream>>>(part, stats);
    final_kernel<<<NTOT / 256, 256, 0, stream>>>(V, stats, e_gg, e_gb, out);
}